// Round 21
// baseline (450.674 us; speedup 1.0000x reference)
//
#include <hip/hip_runtime.h>
#include <hip/hip_bf16.h>

// LGA3D2: out = A_g(A_g(x)); A_g is a 5x5 spatial x 3-depth guided aggregation.
// R22 = R19/R21 (no LDS, G from tap-contiguous packed buffer, DPG=6) with the
// f16 working buffers stored PADDED so the w-window is pure aligned loads:
//   layout [b][c][d+1 (50 rows)][h][264 halves]: 2 zero halves front, 6 back,
//   d=-1 / d=48 rows zeroed. Per depth-row per lane: 2x uint2 load (byte
//   8*lane) + 4 alignbit -> all 8 dot2 pairs. DELETED per row: 3 ds_bpermute
//   (last LDS ops + their serial latency), 3 cndmask, 2 depth branches.

constexpr int RAD = 2;
constexpr int BB = 2, CC = 16, DD = 48, HH = 128, WW = 256;
constexpr int GG = 75;
constexpr int PLANE = HH * WW;

constexpr int WPT = 4;            // outputs per lane along W
constexpr int DPG = 6;            // depths per wave
constexpr int NWV = 4;            // waves per block
constexpr int DCHUNK = DPG * NWV; // 24 depths per block
constexpr int NCH = DD / DCHUNK;  // 2
constexpr int PW = 264;           // padded halves per row: [2][256][6]
constexpr int DP = DD + 2;        // 50 padded depth rows
constexpr size_t PCH = (size_t)DP * HH * PW;          // halves per (b,c): 1,689,600
constexpr size_t PAD_ELEMS = (size_t)BB * CC * PCH;   // 54,067,200 halves
constexpr size_t GPB_UINTS = (size_t)BB * 5 * 9 * PLANE;

using uint = unsigned int;
typedef __attribute__((ext_vector_type(2))) _Float16 half2v;

__device__ __forceinline__ uint pkrtz(float a, float b) {
  return __builtin_bit_cast(uint, __builtin_amdgcn_cvt_pkrtz(a, b));
}
__device__ __forceinline__ float fdot2(uint a, uint b, float c) {
#if __has_builtin(__builtin_amdgcn_fdot2)
  return __builtin_amdgcn_fdot2(__builtin_bit_cast(half2v, a),
                                __builtin_bit_cast(half2v, b), c, false);
#else
  half2v av = __builtin_bit_cast(half2v, a), bv = __builtin_bit_cast(half2v, b);
  return c + (float)av.x * (float)bv.x + (float)av.y * (float)bv.y;
#endif
}
__device__ __forceinline__ uint alignp(uint a, uint b) {  // {lo:b.hi, hi:a.lo}
  return __builtin_amdgcn_alignbit(a, b, 16);
}
__device__ __forceinline__ uint getq(const uint4& v, int q) {
  return q == 0 ? v.x : q == 1 ? v.y : q == 2 ? v.z : v.w;
}

// ---- zero the pads of a padded f16 buffer (w-pads all rows; border d rows)
__global__ __launch_bounds__(256) void zero_pads(unsigned short* __restrict__ buf) {
  const int nrows = (int)(BB * CC * DP * HH);   // 204800
  const int stride = gridDim.x * blockDim.x;
  for (int r = blockIdx.x * blockDim.x + threadIdx.x; r < nrows; r += stride) {
    uint* rowp = reinterpret_cast<uint*>(buf + (size_t)r * PW);
    const int dpad = (r / HH) % DP;
    if (dpad == 0 || dpad == DP - 1) {
      for (int t = 0; t < PW / 2; ++t) rowp[t] = 0u;   // whole border row
    } else {
      rowp[0] = 0u;                                    // halves 0,1
      rowp[129] = 0u; rowp[130] = 0u; rowp[131] = 0u;  // halves 258..263
    }
  }
}

// ---- fp32 -> padded f16 convert (interior only; pads zeroed separately)
__global__ __launch_bounds__(256) void cvt_f32_f16(const float* __restrict__ x,
                                                   unsigned short* __restrict__ xh,
                                                   int n4) {
  const int stride = gridDim.x * blockDim.x;
  for (int i = blockIdx.x * blockDim.x + threadIdx.x; i < n4; i += stride) {
    const float4 v = *reinterpret_cast<const float4*>(x + (size_t)i * 4);
    const uint u0 = pkrtz(v.x, v.y);
    const uint u1 = pkrtz(v.z, v.w);
    const int w4 = (i & 63) * 4;
    const int h = (i >> 6) & (HH - 1);
    const int rest = i >> 13;            // bc*DD + d
    const int d = rest % DD;
    const int bc = rest / DD;
    const size_t hb = ((size_t)(bc * DP + d + 1) * HH + h) * PW + 2 + w4;
    *reinterpret_cast<uint*>(xh + hb) = u0;       // byte 4+8q: 4B aligned
    *reinterpret_cast<uint*>(xh + hb + 2) = u1;
  }
}

// ---- pack g into TAP-CONTIGUOUS f16 j-pair tiles (unchanged from R19).
// uint4 index: (((b*5 + i)*HH + h)*64 + wq)*9 + p   (wq = w/4, p = k*3+jp)
__global__ __launch_bounds__(256) void gpack(const float* __restrict__ g,
                                             uint4* __restrict__ gbuf) {
  const int n = (int)(GPB_UINTS / 4);
  const int stride = gridDim.x * blockDim.x;
  for (int it = blockIdx.x * blockDim.x + threadIdx.x; it < n; it += stride) {
    const int p  = it % 9;
    const int wq = (it / 9) & 63;
    const int h  = (it / (9 * 64)) % HH;
    const int bi = it / (9 * 64 * HH);
    const int i = bi % 5, b = bi / 5;
    const int k = p / 3, jp = p % 3;
    const int chA = (i * 5 + 2 * jp) * 3 + k;
    const float* gb = g + (size_t)b * GG * PLANE + h * WW + 4 * wq;
    const float4 a = *reinterpret_cast<const float4*>(gb + (size_t)chA * PLANE);
    float4 bq = make_float4(0.f, 0.f, 0.f, 0.f);
    if (jp < 2)
      bq = *reinterpret_cast<const float4*>(gb + (size_t)(chA + 3) * PLANE);
    uint4 u;
    u.x = pkrtz(a.x, bq.x); u.y = pkrtz(a.y, bq.y);
    u.z = pkrtz(a.z, bq.z); u.w = pkrtz(a.w, bq.w);
    gbuf[it] = u;
  }
}

// ---- aggregation pass: padded f16 input; OT = ushort (padded y) | float (plain)
template <typename OT, bool PACKED>
__global__ __launch_bounds__(256) void lga_pass(const unsigned short* __restrict__ xp,
                                                const float* __restrict__ g,
                                                const uint4* __restrict__ gpk,
                                                OT* __restrict__ out) {
  constexpr int NWG = BB * CC * NCH * HH;   // 8192
  const int bx = blockIdx.x;
  const int lid = (bx & 7) * (NWG >> 3) + (bx >> 3);
  const int dch = lid % NCH;
  const int h   = (lid / NCH) % HH;
  const int c   = (lid / (NCH * HH)) % CC;
  const int b   =  lid / (NCH * HH * CC);

  const int tid = threadIdx.x;
  const int lane = tid & 63;
  const int dg = tid >> 6;
  const int w0 = lane * WPT;
  const int d0 = dch * DCHUNK + dg * DPG;

  const int ch = b * CC + c;
  const unsigned short* xb = xp + (size_t)ch * PCH;
  const float* gb = g + (size_t)b * GG * PLANE;

  float acc[DPG][WPT];
#pragma unroll
  for (int a = 0; a < DPG; ++a)
#pragma unroll
    for (int q = 0; q < WPT; ++q) acc[a][q] = 0.f;

  const int ilo = (h >= RAD) ? 0 : RAD - h;
  const int him = HH - 1 + RAD - h;
  const int ihi = (him < 4) ? him : 4;

  for (int ii = ilo; ii <= ihi; ++ii) {
    const int hr = h + ii - RAD;

    // G[9]: 144 contiguous bytes per lane
    uint4 G[9];
    if constexpr (PACKED) {
      const uint4* gp = gpk + ((size_t)((b * 5 + ii) * HH + h) * 64 + lane) * 9;
#pragma unroll
      for (int p = 0; p < 9; ++p) G[p] = gp[p];
    } else {
#pragma unroll
      for (int k = 0; k < 3; ++k)
#pragma unroll
        for (int jp = 0; jp < 3; ++jp) {
          const int chA = (ii * 5 + 2 * jp) * 3 + k;
          const float4 a = *reinterpret_cast<const float4*>(
              gb + (size_t)chA * PLANE + h * WW + w0);
          float4 bq = make_float4(0.f, 0.f, 0.f, 0.f);
          if (jp < 2)
            bq = *reinterpret_cast<const float4*>(
                gb + (size_t)(chA + 3) * PLANE + h * WW + w0);
          uint4 u;
          u.x = pkrtz(a.x, bq.x); u.y = pkrtz(a.y, bq.y);
          u.z = pkrtz(a.z, bq.z); u.w = pkrtz(a.w, bq.w);
          G[k * 3 + jp] = u;
        }
    }

#pragma unroll
    for (int a = -1; a <= DPG; ++a) {       // padded rows d0+a+1 in [d0, d0+7]
      // window halves v0..v7 start at padded half (2+w0)-2 = 4*lane
      const size_t rh = ((size_t)(d0 + a + 1) * HH + hr) * PW + 4 * lane;
      const uint2 e01 = *reinterpret_cast<const uint2*>(xb + rh);      // v0..v3
      const uint2 e23 = *reinterpret_cast<const uint2*>(xb + rh + 4);  // v4..v7
      uint P[8];
      P[0] = e01.x; P[2] = e01.y; P[4] = e23.x; P[6] = e23.y;
      P[1] = alignp(P[2], P[0]);
      P[3] = alignp(P[4], P[2]);
      P[5] = alignp(P[6], P[4]);
      P[7] = alignp(P[6], P[6]);            // {v7, v6}: hi half hits packed 0
      // scatter: x row d0+a feeds acc[a+1-k]
#pragma unroll
      for (int k = 0; k < 3; ++k) {
        const int ai = a + 1 - k;
        if (ai < 0 || ai >= DPG) continue;  // compile-time
#pragma unroll
        for (int q = 0; q < WPT; ++q) {
          float t = acc[ai][q];
          t = fdot2(getq(G[k * 3 + 0], q), P[q], t);
          t = fdot2(getq(G[k * 3 + 1], q), P[q + 2], t);
          t = fdot2(getq(G[k * 3 + 2], q), P[q + 4], t);
          acc[ai][q] = t;
        }
      }
    }
  }

  if constexpr (sizeof(OT) == 4) {          // pass2: plain fp32 out
    float* ob = (float*)out + (size_t)ch * DD * PLANE;
    const int obase = d0 * PLANE + h * WW + w0;
#pragma unroll
    for (int ai = 0; ai < DPG; ++ai) {
      float4 t; t.x = acc[ai][0]; t.y = acc[ai][1]; t.z = acc[ai][2]; t.w = acc[ai][3];
      *reinterpret_cast<float4*>(ob + obase + ai * PLANE) = t;
    }
  } else {                                  // pass1: padded f16 y
    unsigned short* ob = (unsigned short*)out + (size_t)ch * PCH;
#pragma unroll
    for (int ai = 0; ai < DPG; ++ai) {
      const size_t hb = ((size_t)(d0 + ai + 1) * HH + h) * PW + 2 + w0;
      *reinterpret_cast<uint*>(ob + hb) = pkrtz(acc[ai][0], acc[ai][1]);
      *reinterpret_cast<uint*>(ob + hb + 2) = pkrtz(acc[ai][2], acc[ai][3]);
    }
  }
}

extern "C" void kernel_launch(void* const* d_in, const int* in_sizes, int n_in,
                              void* d_out, int out_size, void* d_ws, size_t ws_size,
                              hipStream_t stream) {
  const float* x = (const float*)d_in[0];
  const float* g = (const float*)d_in[1];
  float* out = (float*)d_out;

  const size_t elems = (size_t)BB * CC * DD * HH * WW;   // 50,331,648
  // xh (padded f16, 108.1MB) borrows d_out; y (padded f16) at d_ws start.
  // Pass2 reads only d_ws and overwrites d_out (no RAW on xh).
  unsigned short* xh = (unsigned short*)d_out;
  unsigned short* y  = (unsigned short*)d_ws;

  zero_pads<<<1024, 256, 0, stream>>>(xh);
  zero_pads<<<1024, 256, 0, stream>>>(y);
  cvt_f32_f16<<<2048, 256, 0, stream>>>(x, xh, (int)(elems / 4));

  const dim3 grid(BB * CC * NCH * HH);   // 8192
  const dim3 block(64 * NWV);            // 256

  const size_t need = PAD_ELEMS * 2 + GPB_UINTS * 4;   // ~120MB
  if (ws_size >= need) {
    uint4* gbuf = (uint4*)((char*)d_ws + PAD_ELEMS * 2);
    gpack<<<1440, 256, 0, stream>>>(g, gbuf);
    lga_pass<unsigned short, true><<<grid, block, 0, stream>>>(xh, g, gbuf, y);
    lga_pass<float, true><<<grid, block, 0, stream>>>(y, g, gbuf, out);
  } else {
    lga_pass<unsigned short, false><<<grid, block, 0, stream>>>(xh, g, nullptr, y);
    lga_pass<float, false><<<grid, block, 0, stream>>>(y, g, nullptr, out);
  }
}

// Round 22
// 338.275 us; speedup vs baseline: 1.3323x; 1.3323x over previous
//
#include <hip/hip_runtime.h>
#include <hip/hip_bf16.h>

// LGA3D2: out = A_g(A_g(x)); A_g is a 5x5 spatial x 3-depth guided aggregation.
// out[b,c,d,h,w] = sum_{i,j in 5x5, k in 0..2} g[b,(i*5+j)*3+k,h,w] * x[b,c,d+k-1,h+i-2,w+j-2]
// x: [B,C,D,H,W] fp32, g: [B,75,H,W] fp32.
//
// R23 = R19 (best: 348us; bpermute window, no LDS/barriers, tap-contiguous
// packed G, DPG=6) + ONE change: batch-issue all 8 depth-row x loads into
// ownv[8] BEFORE the window/dot2 loop. At VGPR=64 the scheduler could only
// interleave each row's load with ~18 dot2s (~25cyc) vs ~100-200cyc L1
// latency -> one stall per row. Batching forces 8 loads in flight at once
// (live regs ~85 -> compiler must allocate ~96) -> one latency, 8x fewer
// stalls. R22's padded-layout detour regressed (doubled x traffic,
// uncoalesced writes) and is reverted.

constexpr int RAD = 2;
constexpr int BB = 2, CC = 16, DD = 48, HH = 128, WW = 256;
constexpr int GG = 75;
constexpr int PLANE = HH * WW;

constexpr int WPT = 4;            // outputs per lane along W
constexpr int DPG = 6;            // depths per wave
constexpr int NWV = 4;            // waves per block
constexpr int DCHUNK = DPG * NWV; // 24 depths per block
constexpr int NCH = DD / DCHUNK;  // 2
constexpr size_t GPB_UINTS = (size_t)BB * 5 * 9 * PLANE;   // packed G uints

using uint = unsigned int;
typedef __attribute__((ext_vector_type(2))) _Float16 half2v;

__device__ __forceinline__ uint pkrtz(float a, float b) {
  return __builtin_bit_cast(uint, __builtin_amdgcn_cvt_pkrtz(a, b));
}
__device__ __forceinline__ float fdot2(uint a, uint b, float c) {
#if __has_builtin(__builtin_amdgcn_fdot2)
  return __builtin_amdgcn_fdot2(__builtin_bit_cast(half2v, a),
                                __builtin_bit_cast(half2v, b), c, false);
#else
  half2v av = __builtin_bit_cast(half2v, a), bv = __builtin_bit_cast(half2v, b);
  return c + (float)av.x * (float)bv.x + (float)av.y * (float)bv.y;
#endif
}
__device__ __forceinline__ uint alignp(uint a, uint b) {  // {lo:b.hi, hi:a.lo}
  return __builtin_amdgcn_alignbit(a, b, 16);
}
__device__ __forceinline__ unsigned short f2h(float v) {
  return __builtin_bit_cast(unsigned short, (_Float16)v);
}
__device__ __forceinline__ uint getq(const uint4& v, int q) {
  return q == 0 ? v.x : q == 1 ? v.y : q == 2 ? v.z : v.w;
}

// ---- kernel 0: fp32 -> f16 streaming convert
__global__ __launch_bounds__(256) void cvt_f32_f16(const float* __restrict__ x,
                                                   unsigned short* __restrict__ xh,
                                                   int n4) {
  const int stride = gridDim.x * blockDim.x;
  for (int i = blockIdx.x * blockDim.x + threadIdx.x; i < n4; i += stride) {
    const float4 v = *reinterpret_cast<const float4*>(x + (size_t)i * 4);
    uint2 u; u.x = pkrtz(v.x, v.y); u.y = pkrtz(v.z, v.w);
    *reinterpret_cast<uint2*>(xh + (size_t)i * 4) = u;
  }
}

// ---- kernel 0b: pack g into TAP-CONTIGUOUS f16 j-pair tiles.
// uint4 index: (((b*5 + i)*HH + h)*64 + wq)*9 + p   (wq = w/4, p = k*3+jp)
// value.q = {f16 g[(i*5+2jp)*3+k](h,4wq+q), f16 g[(i*5+2jp+1)*3+k](h,4wq+q)|0}
__global__ __launch_bounds__(256) void gpack(const float* __restrict__ g,
                                             uint4* __restrict__ gbuf) {
  const int n = (int)(GPB_UINTS / 4);     // total uint4 items
  const int stride = gridDim.x * blockDim.x;
  for (int it = blockIdx.x * blockDim.x + threadIdx.x; it < n; it += stride) {
    const int p  = it % 9;
    const int wq = (it / 9) & 63;
    const int h  = (it / (9 * 64)) % HH;
    const int bi = it / (9 * 64 * HH);    // b*5 + i
    const int i = bi % 5, b = bi / 5;
    const int k = p / 3, jp = p % 3;
    const int chA = (i * 5 + 2 * jp) * 3 + k;
    const float* gb = g + (size_t)b * GG * PLANE + h * WW + 4 * wq;
    const float4 a = *reinterpret_cast<const float4*>(gb + (size_t)chA * PLANE);
    float4 bq = make_float4(0.f, 0.f, 0.f, 0.f);
    if (jp < 2)
      bq = *reinterpret_cast<const float4*>(gb + (size_t)(chA + 3) * PLANE);
    uint4 u;
    u.x = pkrtz(a.x, bq.x); u.y = pkrtz(a.y, bq.y);
    u.z = pkrtz(a.z, bq.z); u.w = pkrtz(a.w, bq.w);
    gbuf[it] = u;
  }
}

// ---- the aggregation pass: f16 input, OT output (f16 or f32)
template <typename OT, bool PACKED>
__global__ __launch_bounds__(256) void lga_pass(const unsigned short* __restrict__ x,
                                                const float* __restrict__ g,
                                                const uint4* __restrict__ gpk,
                                                OT* __restrict__ out) {
  // XCD-bijective swizzle; dch fastest, then h, c, b.
  constexpr int NWG = BB * CC * NCH * HH;   // 8192
  const int bx = blockIdx.x;
  const int lid = (bx & 7) * (NWG >> 3) + (bx >> 3);
  const int dch = lid % NCH;
  const int h   = (lid / NCH) % HH;
  const int c   = (lid / (NCH * HH)) % CC;
  const int b   =  lid / (NCH * HH * CC);

  const int tid = threadIdx.x;
  const int lane = tid & 63;
  const int dg = tid >> 6;                  // wave index (uniform)
  const int w0 = lane * WPT;
  const int d0 = dch * DCHUNK + dg * DPG;

  const unsigned short* xb = x + (size_t)(b * CC + c) * DD * PLANE;
  const float* gb = g + (size_t)b * GG * PLANE;

  // bpermute byte indices (hoisted)
  const int lm1 = ((lane - 1) & 63) * 4;
  const int lp1 = ((lane + 1) & 63) * 4;
  const bool l0 = (lane == 0);
  const bool l63 = (lane == 63);

  float acc[DPG][WPT];
#pragma unroll
  for (int a = 0; a < DPG; ++a)
#pragma unroll
    for (int q = 0; q < WPT; ++q) acc[a][q] = 0.f;

  const int ilo = (h >= RAD) ? 0 : RAD - h;
  const int him = HH - 1 + RAD - h;
  const int ihi = (him < 4) ? him : 4;

  for (int ii = ilo; ii <= ihi; ++ii) {
    const int hr = h + ii - RAD;

    // G[9]: 144 contiguous bytes per lane (1 base + imm offsets)
    uint4 G[9];
    if constexpr (PACKED) {
      const uint4* gp = gpk + ((size_t)((b * 5 + ii) * HH + h) * 64 + lane) * 9;
#pragma unroll
      for (int p = 0; p < 9; ++p) G[p] = gp[p];
    } else {
#pragma unroll
      for (int k = 0; k < 3; ++k)
#pragma unroll
        for (int jp = 0; jp < 3; ++jp) {
          const int chA = (ii * 5 + 2 * jp) * 3 + k;
          const float4 a = *reinterpret_cast<const float4*>(
              gb + (size_t)chA * PLANE + h * WW + w0);
          float4 bq = make_float4(0.f, 0.f, 0.f, 0.f);
          if (jp < 2)
            bq = *reinterpret_cast<const float4*>(
                gb + (size_t)(chA + 3) * PLANE + h * WW + w0);
          uint4 u;
          u.x = pkrtz(a.x, bq.x); u.y = pkrtz(a.y, bq.y);
          u.z = pkrtz(a.z, bq.z); u.w = pkrtz(a.w, bq.w);
          G[k * 3 + jp] = u;
        }
    }

    // Batch-issue ALL 8 depth-row loads (independent; one L1 latency total).
    uint2 ownv[DPG + 2];
#pragma unroll
    for (int a = -1; a <= DPG; ++a) {
      bool dok = true;
      if (a == -1)  dok = (d0 > 0);         // wave-uniform depth zero-pad
      if (a == DPG) dok = (d0 + DPG < DD);
      ownv[a + 1] = dok ? *reinterpret_cast<const uint2*>(
                              xb + (size_t)(d0 + a) * PLANE + hr * WW + w0)
                        : make_uint2(0u, 0u);
    }

#pragma unroll
    for (int a = -1; a <= DPG; ++a) {       // x depth rows d0-1 .. d0+6
      const uint2 own = ownv[a + 1];

      // 9-uint window P[m] = {w0-2+2m, w0-1+2m} via cross-lane shuffle
      const uint lft = __builtin_amdgcn_ds_bpermute(lm1, (int)own.y);
      const uint rg0 = __builtin_amdgcn_ds_bpermute(lp1, (int)own.x);
      const uint rg1 = __builtin_amdgcn_ds_bpermute(lp1, (int)own.y);
      uint P[9];
      P[0] = l0 ? 0u : lft;                 // {w0-2, w0-1}
      P[2] = own.x; P[4] = own.y;
      P[6] = l63 ? 0u : rg0;                // {w0+4, w0+5}
      P[8] = l63 ? 0u : rg1;                // {w0+6, w0+7} (x*G_pad0 only)
      P[1] = alignp(P[2], P[0]);
      P[3] = alignp(P[4], P[2]);
      P[5] = alignp(P[6], P[4]);
      P[7] = alignp(P[8], P[6]);

      // scatter: x row d0+a feeds acc[a+1-k]; per (k,ai,q): 3 dot2
#pragma unroll
      for (int k = 0; k < 3; ++k) {
        const int ai = a + 1 - k;
        if (ai < 0 || ai >= DPG) continue;  // compile-time
#pragma unroll
        for (int q = 0; q < WPT; ++q) {
          float t = acc[ai][q];
          t = fdot2(getq(G[k * 3 + 0], q), P[q], t);
          t = fdot2(getq(G[k * 3 + 1], q), P[q + 2], t);
          t = fdot2(getq(G[k * 3 + 2], q), P[q + 4], t);
          acc[ai][q] = t;
        }
      }
    }
  }

  const int obase = d0 * PLANE + h * WW + w0;
  if constexpr (sizeof(OT) == 4) {
    float* ob = (float*)out + (size_t)(b * CC + c) * DD * PLANE;
#pragma unroll
    for (int ai = 0; ai < DPG; ++ai) {
      float4 t; t.x = acc[ai][0]; t.y = acc[ai][1]; t.z = acc[ai][2]; t.w = acc[ai][3];
      *reinterpret_cast<float4*>(ob + obase + ai * PLANE) = t;
    }
  } else {
    unsigned short* ob = (unsigned short*)out + (size_t)(b * CC + c) * DD * PLANE;
#pragma unroll
    for (int ai = 0; ai < DPG; ++ai) {
      ushort4 t; t.x = f2h(acc[ai][0]); t.y = f2h(acc[ai][1]);
      t.z = f2h(acc[ai][2]); t.w = f2h(acc[ai][3]);
      *reinterpret_cast<ushort4*>(ob + obase + ai * PLANE) = t;
    }
  }
}

extern "C" void kernel_launch(void* const* d_in, const int* in_sizes, int n_in,
                              void* d_out, int out_size, void* d_ws, size_t ws_size,
                              hipStream_t stream) {
  const float* x = (const float*)d_in[0];
  const float* g = (const float*)d_in[1];
  float* out = (float*)d_out;

  const size_t elems = (size_t)BB * CC * DD * HH * WW;   // 50,331,648
  // xh (f16) borrows d_out's first 100.6MB; y (f16) at d_ws start.
  // Pass2 reads only d_ws (y + gpk) and overwrites d_out.
  unsigned short* xh = (unsigned short*)d_out;
  unsigned short* y  = (unsigned short*)d_ws;

  cvt_f32_f16<<<2048, 256, 0, stream>>>(x, xh, (int)(elems / 4));

  const dim3 grid(BB * CC * NCH * HH);   // 8192
  const dim3 block(64 * NWV);            // 256

  // Packed-G buffer lives after y in d_ws if it fits (y:100.6MB + gpk:11.8MB).
  const size_t need = elems * 2 + GPB_UINTS * 4;
  if (ws_size >= need) {
    uint4* gbuf = (uint4*)((char*)d_ws + elems * 2);
    gpack<<<1440, 256, 0, stream>>>(g, gbuf);
    lga_pass<unsigned short, true><<<grid, block, 0, stream>>>(xh, g, gbuf, y);
    lga_pass<float, true><<<grid, block, 0, stream>>>(y, g, gbuf, out);
  } else {
    lga_pass<unsigned short, false><<<grid, block, 0, stream>>>(xh, g, nullptr, y);
    lga_pass<float, false><<<grid, block, 0, stream>>>(y, g, nullptr, out);
  }
}

// Round 23
// 332.000 us; speedup vs baseline: 1.3575x; 1.0189x over previous
//
#include <hip/hip_runtime.h>
#include <hip/hip_bf16.h>

// LGA3D2: out = A_g(A_g(x)); A_g is a 5x5 spatial x 3-depth guided aggregation.
// out[b,c,d,h,w] = sum_{i,j in 5x5, k in 0..2} g[b,(i*5+j)*3+k,h,w] * x[b,c,d+k-1,h+i-2,w+j-2]
// x: [B,C,D,H,W] fp32, g: [B,75,H,W] fp32.
//
// R24 = R23 (batch row loads, bpermute window, no LDS/barriers, tap-contiguous
// packed G) with deeper per-wave depth coverage: DPG 6->8, NWV 4->6
// (block=384, DCHUNK=48, NCH=1). G's 144B/lane/tap now serves 32 outputs
// (-25% G L1 traffic + addressing); no dch indexing; 10-row load batch.
// Live regs ~95 (acc 32 + G 36 + ownv 20) -- between proven-good 52 and the
// 132-register occupancy cliff.

constexpr int RAD = 2;
constexpr int BB = 2, CC = 16, DD = 48, HH = 128, WW = 256;
constexpr int GG = 75;
constexpr int PLANE = HH * WW;

constexpr int WPT = 4;            // outputs per lane along W
constexpr int DPG = 8;            // depths per wave
constexpr int NWV = 6;            // waves per block (384 threads)
constexpr int DCHUNK = DPG * NWV; // 48 = full D per block
constexpr size_t GPB_UINTS = (size_t)BB * 5 * 9 * PLANE;   // packed G uints

using uint = unsigned int;
typedef __attribute__((ext_vector_type(2))) _Float16 half2v;

__device__ __forceinline__ uint pkrtz(float a, float b) {
  return __builtin_bit_cast(uint, __builtin_amdgcn_cvt_pkrtz(a, b));
}
__device__ __forceinline__ float fdot2(uint a, uint b, float c) {
#if __has_builtin(__builtin_amdgcn_fdot2)
  return __builtin_amdgcn_fdot2(__builtin_bit_cast(half2v, a),
                                __builtin_bit_cast(half2v, b), c, false);
#else
  half2v av = __builtin_bit_cast(half2v, a), bv = __builtin_bit_cast(half2v, b);
  return c + (float)av.x * (float)bv.x + (float)av.y * (float)bv.y;
#endif
}
__device__ __forceinline__ uint alignp(uint a, uint b) {  // {lo:b.hi, hi:a.lo}
  return __builtin_amdgcn_alignbit(a, b, 16);
}
__device__ __forceinline__ unsigned short f2h(float v) {
  return __builtin_bit_cast(unsigned short, (_Float16)v);
}
__device__ __forceinline__ uint getq(const uint4& v, int q) {
  return q == 0 ? v.x : q == 1 ? v.y : q == 2 ? v.z : v.w;
}

// ---- kernel 0: fp32 -> f16 streaming convert
__global__ __launch_bounds__(256) void cvt_f32_f16(const float* __restrict__ x,
                                                   unsigned short* __restrict__ xh,
                                                   int n4) {
  const int stride = gridDim.x * blockDim.x;
  for (int i = blockIdx.x * blockDim.x + threadIdx.x; i < n4; i += stride) {
    const float4 v = *reinterpret_cast<const float4*>(x + (size_t)i * 4);
    uint2 u; u.x = pkrtz(v.x, v.y); u.y = pkrtz(v.z, v.w);
    *reinterpret_cast<uint2*>(xh + (size_t)i * 4) = u;
  }
}

// ---- kernel 0b: pack g into TAP-CONTIGUOUS f16 j-pair tiles.
// uint4 index: (((b*5 + i)*HH + h)*64 + wq)*9 + p   (wq = w/4, p = k*3+jp)
// value.q = {f16 g[(i*5+2jp)*3+k](h,4wq+q), f16 g[(i*5+2jp+1)*3+k](h,4wq+q)|0}
__global__ __launch_bounds__(256) void gpack(const float* __restrict__ g,
                                             uint4* __restrict__ gbuf) {
  const int n = (int)(GPB_UINTS / 4);     // total uint4 items
  const int stride = gridDim.x * blockDim.x;
  for (int it = blockIdx.x * blockDim.x + threadIdx.x; it < n; it += stride) {
    const int p  = it % 9;
    const int wq = (it / 9) & 63;
    const int h  = (it / (9 * 64)) % HH;
    const int bi = it / (9 * 64 * HH);    // b*5 + i
    const int i = bi % 5, b = bi / 5;
    const int k = p / 3, jp = p % 3;
    const int chA = (i * 5 + 2 * jp) * 3 + k;
    const float* gb = g + (size_t)b * GG * PLANE + h * WW + 4 * wq;
    const float4 a = *reinterpret_cast<const float4*>(gb + (size_t)chA * PLANE);
    float4 bq = make_float4(0.f, 0.f, 0.f, 0.f);
    if (jp < 2)
      bq = *reinterpret_cast<const float4*>(gb + (size_t)(chA + 3) * PLANE);
    uint4 u;
    u.x = pkrtz(a.x, bq.x); u.y = pkrtz(a.y, bq.y);
    u.z = pkrtz(a.z, bq.z); u.w = pkrtz(a.w, bq.w);
    gbuf[it] = u;
  }
}

// ---- the aggregation pass: f16 input, OT output (f16 or f32)
template <typename OT, bool PACKED>
__global__ __launch_bounds__(64 * NWV) void lga_pass(const unsigned short* __restrict__ x,
                                                     const float* __restrict__ g,
                                                     const uint4* __restrict__ gpk,
                                                     OT* __restrict__ out) {
  // XCD-bijective swizzle; h fastest, then c, b.
  constexpr int NWG = BB * CC * HH;   // 4096
  const int bx = blockIdx.x;
  const int lid = (bx & 7) * (NWG >> 3) + (bx >> 3);
  const int h = lid % HH;
  const int c = (lid / HH) % CC;
  const int b = lid / (HH * CC);

  const int tid = threadIdx.x;
  const int lane = tid & 63;
  const int dg = tid >> 6;                  // wave index (uniform)
  const int w0 = lane * WPT;
  const int d0 = dg * DPG;

  const unsigned short* xb = x + (size_t)(b * CC + c) * DD * PLANE;
  const float* gb = g + (size_t)b * GG * PLANE;

  // bpermute byte indices (hoisted)
  const int lm1 = ((lane - 1) & 63) * 4;
  const int lp1 = ((lane + 1) & 63) * 4;
  const bool l0 = (lane == 0);
  const bool l63 = (lane == 63);

  float acc[DPG][WPT];
#pragma unroll
  for (int a = 0; a < DPG; ++a)
#pragma unroll
    for (int q = 0; q < WPT; ++q) acc[a][q] = 0.f;

  const int ilo = (h >= RAD) ? 0 : RAD - h;
  const int him = HH - 1 + RAD - h;
  const int ihi = (him < 4) ? him : 4;

  for (int ii = ilo; ii <= ihi; ++ii) {
    const int hr = h + ii - RAD;

    // G[9]: 144 contiguous bytes per lane (1 base + imm offsets)
    uint4 G[9];
    if constexpr (PACKED) {
      const uint4* gp = gpk + ((size_t)((b * 5 + ii) * HH + h) * 64 + lane) * 9;
#pragma unroll
      for (int p = 0; p < 9; ++p) G[p] = gp[p];
    } else {
#pragma unroll
      for (int k = 0; k < 3; ++k)
#pragma unroll
        for (int jp = 0; jp < 3; ++jp) {
          const int chA = (ii * 5 + 2 * jp) * 3 + k;
          const float4 a = *reinterpret_cast<const float4*>(
              gb + (size_t)chA * PLANE + h * WW + w0);
          float4 bq = make_float4(0.f, 0.f, 0.f, 0.f);
          if (jp < 2)
            bq = *reinterpret_cast<const float4*>(
                gb + (size_t)(chA + 3) * PLANE + h * WW + w0);
          uint4 u;
          u.x = pkrtz(a.x, bq.x); u.y = pkrtz(a.y, bq.y);
          u.z = pkrtz(a.z, bq.z); u.w = pkrtz(a.w, bq.w);
          G[k * 3 + jp] = u;
        }
    }

    // Batch-issue ALL 10 depth-row loads (independent; one L1 latency total).
    uint2 ownv[DPG + 2];
#pragma unroll
    for (int a = -1; a <= DPG; ++a) {
      bool dok = true;
      if (a == -1)  dok = (d0 > 0);         // wave-uniform depth zero-pad
      if (a == DPG) dok = (d0 + DPG < DD);
      ownv[a + 1] = dok ? *reinterpret_cast<const uint2*>(
                              xb + (size_t)(d0 + a) * PLANE + hr * WW + w0)
                        : make_uint2(0u, 0u);
    }

#pragma unroll
    for (int a = -1; a <= DPG; ++a) {       // x depth rows d0-1 .. d0+8
      const uint2 own = ownv[a + 1];

      // 9-uint window P[m] = {w0-2+2m, w0-1+2m} via cross-lane shuffle
      const uint lft = __builtin_amdgcn_ds_bpermute(lm1, (int)own.y);
      const uint rg0 = __builtin_amdgcn_ds_bpermute(lp1, (int)own.x);
      const uint rg1 = __builtin_amdgcn_ds_bpermute(lp1, (int)own.y);
      uint P[9];
      P[0] = l0 ? 0u : lft;                 // {w0-2, w0-1}
      P[2] = own.x; P[4] = own.y;
      P[6] = l63 ? 0u : rg0;                // {w0+4, w0+5}
      P[8] = l63 ? 0u : rg1;                // {w0+6, w0+7} (x*G_pad0 only)
      P[1] = alignp(P[2], P[0]);
      P[3] = alignp(P[4], P[2]);
      P[5] = alignp(P[6], P[4]);
      P[7] = alignp(P[8], P[6]);

      // scatter: x row d0+a feeds acc[a+1-k]; per (k,ai,q): 3 dot2
#pragma unroll
      for (int k = 0; k < 3; ++k) {
        const int ai = a + 1 - k;
        if (ai < 0 || ai >= DPG) continue;  // compile-time
#pragma unroll
        for (int q = 0; q < WPT; ++q) {
          float t = acc[ai][q];
          t = fdot2(getq(G[k * 3 + 0], q), P[q], t);
          t = fdot2(getq(G[k * 3 + 1], q), P[q + 2], t);
          t = fdot2(getq(G[k * 3 + 2], q), P[q + 4], t);
          acc[ai][q] = t;
        }
      }
    }
  }

  const int obase = d0 * PLANE + h * WW + w0;
  if constexpr (sizeof(OT) == 4) {
    float* ob = (float*)out + (size_t)(b * CC + c) * DD * PLANE;
#pragma unroll
    for (int ai = 0; ai < DPG; ++ai) {
      float4 t; t.x = acc[ai][0]; t.y = acc[ai][1]; t.z = acc[ai][2]; t.w = acc[ai][3];
      *reinterpret_cast<float4*>(ob + obase + ai * PLANE) = t;
    }
  } else {
    unsigned short* ob = (unsigned short*)out + (size_t)(b * CC + c) * DD * PLANE;
#pragma unroll
    for (int ai = 0; ai < DPG; ++ai) {
      ushort4 t; t.x = f2h(acc[ai][0]); t.y = f2h(acc[ai][1]);
      t.z = f2h(acc[ai][2]); t.w = f2h(acc[ai][3]);
      *reinterpret_cast<ushort4*>(ob + obase + ai * PLANE) = t;
    }
  }
}

extern "C" void kernel_launch(void* const* d_in, const int* in_sizes, int n_in,
                              void* d_out, int out_size, void* d_ws, size_t ws_size,
                              hipStream_t stream) {
  const float* x = (const float*)d_in[0];
  const float* g = (const float*)d_in[1];
  float* out = (float*)d_out;

  const size_t elems = (size_t)BB * CC * DD * HH * WW;   // 50,331,648
  // xh (f16) borrows d_out's first 100.6MB; y (f16) at d_ws start.
  // Pass2 reads only d_ws (y + gpk) and overwrites d_out.
  unsigned short* xh = (unsigned short*)d_out;
  unsigned short* y  = (unsigned short*)d_ws;

  cvt_f32_f16<<<2048, 256, 0, stream>>>(x, xh, (int)(elems / 4));

  const dim3 grid(BB * CC * HH);   // 4096
  const dim3 block(64 * NWV);      // 384

  // Packed-G buffer lives after y in d_ws if it fits (y:100.6MB + gpk:11.8MB).
  const size_t need = elems * 2 + GPB_UINTS * 4;
  if (ws_size >= need) {
    uint4* gbuf = (uint4*)((char*)d_ws + elems * 2);
    gpack<<<1440, 256, 0, stream>>>(g, gbuf);
    lga_pass<unsigned short, true><<<grid, block, 0, stream>>>(xh, g, gbuf, y);
    lga_pass<float, true><<<grid, block, 0, stream>>>(y, g, gbuf, out);
  } else {
    lga_pass<unsigned short, false><<<grid, block, 0, stream>>>(xh, g, nullptr, y);
    lga_pass<float, false><<<grid, block, 0, stream>>>(y, g, nullptr, out);
  }
}

// Round 24
// 322.490 us; speedup vs baseline: 1.3975x; 1.0295x over previous
//
#include <hip/hip_runtime.h>
#include <hip/hip_bf16.h>

// LGA3D2: out = A_g(A_g(x)); A_g is a 5x5 spatial x 3-depth guided aggregation.
// out[b,c,d,h,w] = sum_{i,j in 5x5, k in 0..2} g[b,(i*5+j)*3+k,h,w] * x[b,c,d+k-1,h+i-2,w+j-2]
// x: [B,C,D,H,W] fp32, g: [B,75,H,W] fp32.
//
// R25 = R24 (DPG=8, NWV=6, batch row loads, bpermute window, no LDS/barriers,
// tap-contiguous packed G) with the cvt dispatch FUSED into pass1:
//   pass1 reads fp32 x directly (uint4 batch loads, 2x pkrtz per row after
//   the batch) -> the standalone cvt kernel (201MB R + 100MB W ~= 29us) is
//   deleted, and d_out no longer doubles as xh storage.
//   Cost: pass1 FETCH ~140 -> ~240MB (pass runs at 12% HBM peak -> hidden),
//   +20 pkrtz/tap, transient +40 VGPR (raw uint4[10]).

constexpr int RAD = 2;
constexpr int BB = 2, CC = 16, DD = 48, HH = 128, WW = 256;
constexpr int GG = 75;
constexpr int PLANE = HH * WW;

constexpr int WPT = 4;            // outputs per lane along W
constexpr int DPG = 8;            // depths per wave
constexpr int NWV = 6;            // waves per block (384 threads)
constexpr int DCHUNK = DPG * NWV; // 48 = full D per block
constexpr size_t GPB_UINTS = (size_t)BB * 5 * 9 * PLANE;   // packed G uints

using uint = unsigned int;
typedef __attribute__((ext_vector_type(2))) _Float16 half2v;

__device__ __forceinline__ uint pkrtz(float a, float b) {
  return __builtin_bit_cast(uint, __builtin_amdgcn_cvt_pkrtz(a, b));
}
__device__ __forceinline__ float fdot2(uint a, uint b, float c) {
#if __has_builtin(__builtin_amdgcn_fdot2)
  return __builtin_amdgcn_fdot2(__builtin_bit_cast(half2v, a),
                                __builtin_bit_cast(half2v, b), c, false);
#else
  half2v av = __builtin_bit_cast(half2v, a), bv = __builtin_bit_cast(half2v, b);
  return c + (float)av.x * (float)bv.x + (float)av.y * (float)bv.y;
#endif
}
__device__ __forceinline__ uint alignp(uint a, uint b) {  // {lo:b.hi, hi:a.lo}
  return __builtin_amdgcn_alignbit(a, b, 16);
}
__device__ __forceinline__ unsigned short f2h(float v) {
  return __builtin_bit_cast(unsigned short, (_Float16)v);
}
__device__ __forceinline__ uint getq(const uint4& v, int q) {
  return q == 0 ? v.x : q == 1 ? v.y : q == 2 ? v.z : v.w;
}

// ---- pack g into TAP-CONTIGUOUS f16 j-pair tiles.
// uint4 index: (((b*5 + i)*HH + h)*64 + wq)*9 + p   (wq = w/4, p = k*3+jp)
// value.q = {f16 g[(i*5+2jp)*3+k](h,4wq+q), f16 g[(i*5+2jp+1)*3+k](h,4wq+q)|0}
__global__ __launch_bounds__(256) void gpack(const float* __restrict__ g,
                                             uint4* __restrict__ gbuf) {
  const int n = (int)(GPB_UINTS / 4);     // total uint4 items
  const int stride = gridDim.x * blockDim.x;
  for (int it = blockIdx.x * blockDim.x + threadIdx.x; it < n; it += stride) {
    const int p  = it % 9;
    const int wq = (it / 9) & 63;
    const int h  = (it / (9 * 64)) % HH;
    const int bi = it / (9 * 64 * HH);    // b*5 + i
    const int i = bi % 5, b = bi / 5;
    const int k = p / 3, jp = p % 3;
    const int chA = (i * 5 + 2 * jp) * 3 + k;
    const float* gb = g + (size_t)b * GG * PLANE + h * WW + 4 * wq;
    const float4 a = *reinterpret_cast<const float4*>(gb + (size_t)chA * PLANE);
    float4 bq = make_float4(0.f, 0.f, 0.f, 0.f);
    if (jp < 2)
      bq = *reinterpret_cast<const float4*>(gb + (size_t)(chA + 3) * PLANE);
    uint4 u;
    u.x = pkrtz(a.x, bq.x); u.y = pkrtz(a.y, bq.y);
    u.z = pkrtz(a.z, bq.z); u.w = pkrtz(a.w, bq.w);
    gbuf[it] = u;
  }
}

// ---- the aggregation pass.
// IT=float: read fp32 x directly (fused convert). IT=ushort: f16 input.
// OT=ushort: f16 out (pass1 -> y). OT=float: fp32 out (pass2 -> result).
template <typename IT, typename OT, bool PACKED>
__global__ __launch_bounds__(64 * NWV) void lga_pass(const IT* __restrict__ x,
                                                     const float* __restrict__ g,
                                                     const uint4* __restrict__ gpk,
                                                     OT* __restrict__ out) {
  constexpr bool F32IN = (sizeof(IT) == 4);
  // XCD-bijective swizzle; h fastest, then c, b.
  constexpr int NWG = BB * CC * HH;   // 4096
  const int bx = blockIdx.x;
  const int lid = (bx & 7) * (NWG >> 3) + (bx >> 3);
  const int h = lid % HH;
  const int c = (lid / HH) % CC;
  const int b = lid / (HH * CC);

  const int tid = threadIdx.x;
  const int lane = tid & 63;
  const int dg = tid >> 6;                  // wave index (uniform)
  const int w0 = lane * WPT;
  const int d0 = dg * DPG;

  const IT* xb = x + (size_t)(b * CC + c) * DD * PLANE;
  const float* gb = g + (size_t)b * GG * PLANE;

  // bpermute byte indices (hoisted)
  const int lm1 = ((lane - 1) & 63) * 4;
  const int lp1 = ((lane + 1) & 63) * 4;
  const bool l0 = (lane == 0);
  const bool l63 = (lane == 63);

  float acc[DPG][WPT];
#pragma unroll
  for (int a = 0; a < DPG; ++a)
#pragma unroll
    for (int q = 0; q < WPT; ++q) acc[a][q] = 0.f;

  const int ilo = (h >= RAD) ? 0 : RAD - h;
  const int him = HH - 1 + RAD - h;
  const int ihi = (him < 4) ? him : 4;

  for (int ii = ilo; ii <= ihi; ++ii) {
    const int hr = h + ii - RAD;

    // G[9]: 144 contiguous bytes per lane (1 base + imm offsets)
    uint4 G[9];
    if constexpr (PACKED) {
      const uint4* gp = gpk + ((size_t)((b * 5 + ii) * HH + h) * 64 + lane) * 9;
#pragma unroll
      for (int p = 0; p < 9; ++p) G[p] = gp[p];
    } else {
#pragma unroll
      for (int k = 0; k < 3; ++k)
#pragma unroll
        for (int jp = 0; jp < 3; ++jp) {
          const int chA = (ii * 5 + 2 * jp) * 3 + k;
          const float4 a = *reinterpret_cast<const float4*>(
              gb + (size_t)chA * PLANE + h * WW + w0);
          float4 bq = make_float4(0.f, 0.f, 0.f, 0.f);
          if (jp < 2)
            bq = *reinterpret_cast<const float4*>(
                gb + (size_t)(chA + 3) * PLANE + h * WW + w0);
          uint4 u;
          u.x = pkrtz(a.x, bq.x); u.y = pkrtz(a.y, bq.y);
          u.z = pkrtz(a.z, bq.z); u.w = pkrtz(a.w, bq.w);
          G[k * 3 + jp] = u;
        }
    }

    // Batch-issue ALL depth-row loads (independent; one L1 latency total).
    uint2 ownv[DPG + 2];
    if constexpr (F32IN) {
      uint4 raw[DPG + 2];
#pragma unroll
      for (int a = -1; a <= DPG; ++a) {
        bool dok = true;
        if (a == -1)  dok = (d0 > 0);
        if (a == DPG) dok = (d0 + DPG < DD);
        raw[a + 1] = dok ? *reinterpret_cast<const uint4*>(
                               xb + (size_t)(d0 + a) * PLANE + hr * WW + w0)
                         : make_uint4(0u, 0u, 0u, 0u);
      }
#pragma unroll
      for (int a = 0; a < DPG + 2; ++a) {
        ownv[a].x = pkrtz(__uint_as_float(raw[a].x), __uint_as_float(raw[a].y));
        ownv[a].y = pkrtz(__uint_as_float(raw[a].z), __uint_as_float(raw[a].w));
      }
    } else {
#pragma unroll
      for (int a = -1; a <= DPG; ++a) {
        bool dok = true;
        if (a == -1)  dok = (d0 > 0);
        if (a == DPG) dok = (d0 + DPG < DD);
        ownv[a + 1] = dok ? *reinterpret_cast<const uint2*>(
                                xb + (size_t)(d0 + a) * PLANE + hr * WW + w0)
                          : make_uint2(0u, 0u);
      }
    }

#pragma unroll
    for (int a = -1; a <= DPG; ++a) {       // x depth rows d0-1 .. d0+8
      const uint2 own = ownv[a + 1];

      // 9-uint window P[m] = {w0-2+2m, w0-1+2m} via cross-lane shuffle
      const uint lft = __builtin_amdgcn_ds_bpermute(lm1, (int)own.y);
      const uint rg0 = __builtin_amdgcn_ds_bpermute(lp1, (int)own.x);
      const uint rg1 = __builtin_amdgcn_ds_bpermute(lp1, (int)own.y);
      uint P[9];
      P[0] = l0 ? 0u : lft;                 // {w0-2, w0-1}
      P[2] = own.x; P[4] = own.y;
      P[6] = l63 ? 0u : rg0;                // {w0+4, w0+5}
      P[8] = l63 ? 0u : rg1;                // {w0+6, w0+7} (x*G_pad0 only)
      P[1] = alignp(P[2], P[0]);
      P[3] = alignp(P[4], P[2]);
      P[5] = alignp(P[6], P[4]);
      P[7] = alignp(P[8], P[6]);

      // scatter: x row d0+a feeds acc[a+1-k]; per (k,ai,q): 3 dot2
#pragma unroll
      for (int k = 0; k < 3; ++k) {
        const int ai = a + 1 - k;
        if (ai < 0 || ai >= DPG) continue;  // compile-time
#pragma unroll
        for (int q = 0; q < WPT; ++q) {
          float t = acc[ai][q];
          t = fdot2(getq(G[k * 3 + 0], q), P[q], t);
          t = fdot2(getq(G[k * 3 + 1], q), P[q + 2], t);
          t = fdot2(getq(G[k * 3 + 2], q), P[q + 4], t);
          acc[ai][q] = t;
        }
      }
    }
  }

  const int obase = d0 * PLANE + h * WW + w0;
  if constexpr (sizeof(OT) == 4) {
    float* ob = (float*)out + (size_t)(b * CC + c) * DD * PLANE;
#pragma unroll
    for (int ai = 0; ai < DPG; ++ai) {
      float4 t; t.x = acc[ai][0]; t.y = acc[ai][1]; t.z = acc[ai][2]; t.w = acc[ai][3];
      *reinterpret_cast<float4*>(ob + obase + ai * PLANE) = t;
    }
  } else {
    unsigned short* ob = (unsigned short*)out + (size_t)(b * CC + c) * DD * PLANE;
#pragma unroll
    for (int ai = 0; ai < DPG; ++ai) {
      ushort4 t; t.x = f2h(acc[ai][0]); t.y = f2h(acc[ai][1]);
      t.z = f2h(acc[ai][2]); t.w = f2h(acc[ai][3]);
      *reinterpret_cast<ushort4*>(ob + obase + ai * PLANE) = t;
    }
  }
}

extern "C" void kernel_launch(void* const* d_in, const int* in_sizes, int n_in,
                              void* d_out, int out_size, void* d_ws, size_t ws_size,
                              hipStream_t stream) {
  const float* x = (const float*)d_in[0];
  const float* g = (const float*)d_in[1];
  float* out = (float*)d_out;

  const size_t elems = (size_t)BB * CC * DD * HH * WW;   // 50,331,648
  unsigned short* y = (unsigned short*)d_ws;             // f16 intermediate

  const dim3 grid(BB * CC * HH);   // 4096
  const dim3 block(64 * NWV);      // 384

  // Packed-G buffer lives after y in d_ws if it fits (y:100.6MB + gpk:11.8MB).
  const size_t need = elems * 2 + GPB_UINTS * 4;
  if (ws_size >= need) {
    uint4* gbuf = (uint4*)((char*)d_ws + elems * 2);
    gpack<<<1440, 256, 0, stream>>>(g, gbuf);
    lga_pass<float, unsigned short, true><<<grid, block, 0, stream>>>(x, g, gbuf, y);
    lga_pass<unsigned short, float, true><<<grid, block, 0, stream>>>(y, g, gbuf, out);
  } else {
    lga_pass<float, unsigned short, false><<<grid, block, 0, stream>>>(x, g, nullptr, y);
    lga_pass<unsigned short, float, false><<<grid, block, 0, stream>>>(y, g, nullptr, out);
  }
}